// Round 2
// baseline (864.085 us; speedup 1.0000x reference)
//
#include <hip/hip_runtime.h>
#include <math.h>

#define NN 768
#define CSn 384
#define CZn 128
#define Cn 16
#define Hn 12
#define PQn 4
#define PVn 8
#define CONCATn 2112
#define LGS 772   // logits LDS row stride (768 + 4: bank-decorrelates h, keeps 16B align)

// ---------------------------------------------------------------------------
// Kernel 1: input projections.  96 blocks x 8 rows each.
//   q,k,v        : [N][H][C]
//   q_pts        : [N][H][PQ][3] (global frame)
//   k_pts        : [N][H][PQ][3], v_pts : [N][H][PV][3]
// ---------------------------------------------------------------------------
__global__ __launch_bounds__(256) void proj_kernel(
    const float* __restrict__ s, const float* __restrict__ rot, const float* __restrict__ trans,
    const float* __restrict__ Wq, const float* __restrict__ bq,
    const float* __restrict__ Wkv, const float* __restrict__ bkv,
    const float* __restrict__ Wqp, const float* __restrict__ bqp,
    const float* __restrict__ Wkvp, const float* __restrict__ bkvp,
    float* __restrict__ q, float* __restrict__ k, float* __restrict__ v,
    float* __restrict__ q_pts, float* __restrict__ k_pts, float* __restrict__ v_pts)
{
    const int rt = blockIdx.x;         // 0..95
    const int t  = threadIdx.x;
    const int r0 = rt * 8;
    __shared__ float sl[8][CSn];       // 12 KB
    __shared__ float lin[8][1152];     // 36.9 KB

    const float4* s4 = (const float4*)(s + (size_t)r0 * CSn);
    for (int idx = t; idx < 8 * CSn / 4; idx += 256)
        ((float4*)&sl[0][0])[idx] = s4[idx];
    __syncthreads();

    // 1152 output columns as 288 float4 slots
    for (int slot = t; slot < 288; slot += 256) {
        const int col = slot * 4;
        const float* W; const float* bias; int cw; int fout;
        if (col < 192)      { W = Wq;   bias = bq;   cw = col;       fout = 192; }
        else if (col < 576) { W = Wkv;  bias = bkv;  cw = col - 192; fout = 384; }
        else if (col < 720) { W = Wqp;  bias = bqp;  cw = col - 576; fout = 144; }
        else                { W = Wkvp; bias = bkvp; cw = col - 720; fout = 432; }
        float4 bv = *(const float4*)(bias + cw);
        float4 acc[8];
        #pragma unroll
        for (int r = 0; r < 8; ++r) acc[r] = bv;
        const float* Wp = W + cw;
        for (int kk = 0; kk < CSn; ++kk) {
            float4 w = *(const float4*)(Wp + (size_t)kk * fout);
            #pragma unroll
            for (int r = 0; r < 8; ++r) {
                float cv = sl[r][kk];
                acc[r].x += cv * w.x; acc[r].y += cv * w.y;
                acc[r].z += cv * w.z; acc[r].w += cv * w.w;
            }
        }
        #pragma unroll
        for (int r = 0; r < 8; ++r) *(float4*)&lin[r][col] = acc[r];
    }
    __syncthreads();

    for (int r = 0; r < 8; ++r) {
        const int i = r0 + r;
        if (t < 192) q[(size_t)i * 192 + t] = lin[r][t];
        // k/v scatter: 384 columns, 256 threads -> stride loop (BUGFIX R1:
        // was `if (t < 384)` which never covered cols 256..383, i.e. heads 8-11)
        for (int tt = t; tt < 384; tt += 256) {
            const int h = tt >> 5, cc = tt & 31;
            const float val = lin[r][192 + tt];
            if (cc < 16) k[((size_t)i * Hn + h) * Cn + cc] = val;
            else         v[((size_t)i * Hn + h) * Cn + (cc - 16)] = val;
        }
        const float R0 = rot[i*9+0], R1 = rot[i*9+1], R2 = rot[i*9+2];
        const float R3 = rot[i*9+3], R4 = rot[i*9+4], R5 = rot[i*9+5];
        const float R6 = rot[i*9+6], R7 = rot[i*9+7], R8 = rot[i*9+8];
        const float T0 = trans[i*3+0], T1 = trans[i*3+1], T2 = trans[i*3+2];
        if (t < 48) {   // q points: lin[576 + x*48 + hp]
            const float px = lin[r][576 + t], py = lin[r][576 + 48 + t], pz = lin[r][576 + 96 + t];
            const float gx = R0*px + R1*py + R2*pz + T0;
            const float gy = R3*px + R4*py + R5*pz + T1;
            const float gz = R6*px + R7*py + R8*pz + T2;
            float* qp = q_pts + ((size_t)i * 48 + t) * 3;
            qp[0] = gx; qp[1] = gy; qp[2] = gz;
        }
        if (t < 144) {  // kv points: lin[720 + x*144 + hp]
            const float px = lin[r][720 + t], py = lin[r][720 + 144 + t], pz = lin[r][720 + 288 + t];
            const float gx = R0*px + R1*py + R2*pz + T0;
            const float gy = R3*px + R4*py + R5*pz + T1;
            const float gz = R6*px + R7*py + R8*pz + T2;
            const int h = t / 12, pp = t % 12;
            float* dst = (pp < 4) ? (k_pts + ((size_t)i * Hn + h) * PQn * 3 + pp * 3)
                                  : (v_pts + ((size_t)i * Hn + h) * PVn * 3 + (pp - 4) * 3);
            dst[0] = gx; dst[1] = gy; dst[2] = gz;
        }
    }
}

// ---------------------------------------------------------------------------
// Kernel 2: per-row fused IPA.  One block per query row i.
// ---------------------------------------------------------------------------
__global__ __launch_bounds__(256) void row_kernel(
    const float* __restrict__ z, const float* __restrict__ mask,
    const float* __restrict__ rot, const float* __restrict__ trans,
    const float* __restrict__ q, const float* __restrict__ k, const float* __restrict__ v,
    const float* __restrict__ q_pts, const float* __restrict__ k_pts, const float* __restrict__ v_pts,
    const float* __restrict__ Wb, const float* __restrict__ bb, const float* __restrict__ head_w,
    float* __restrict__ cat)
{
    const int i = blockIdx.x;
    const int t = threadIdx.x;
    __shared__ float lg[Hn * LGS];        // 37056 B : logits / attention
    __shared__ float part[2][Hn * CZn];   // 12288 B : o_pair partials
    __shared__ float ptsum[Hn * PVn * 3]; // 1152  B : o_pt raw sums

    const float S_QK = 0.14433756729740643f;   // sqrt(1/48)
    const float S_B  = 0.5773502691896258f;    // sqrt(1/3)
    const float S_PT = 0.1360827634879543f;    // sqrt(1/54)
    float coef[12];
    #pragma unroll
    for (int h = 0; h < 12; ++h) coef[h] = -0.5f * S_PT * log1pf(expf(head_w[h]));
    const float mi = mask[i];

    // ---------------- Phase A: logits (z@Wb + qk + point attention) --------
    const float* qrow  = q     + (size_t)i * Hn * Cn;
    const float* qprow = q_pts + (size_t)i * Hn * PQn * 3;
    #pragma unroll 1
    for (int jj = 0; jj < 3; ++jj) {
        const int j = t + jj * 256;
        const float4* zr = (const float4*)(z + ((size_t)i * NN + j) * CZn);
        float bh[12];
        #pragma unroll
        for (int h = 0; h < 12; ++h) bh[h] = bb[h];
        #pragma unroll 4
        for (int c4 = 0; c4 < 32; ++c4) {
            float4 zv = zr[c4];
            #pragma unroll
            for (int h = 0; h < 12; ++h) {
                bh[h] += zv.x * Wb[(c4*4+0)*12 + h] + zv.y * Wb[(c4*4+1)*12 + h]
                       + zv.z * Wb[(c4*4+2)*12 + h] + zv.w * Wb[(c4*4+3)*12 + h];
            }
        }
        const float mterm = 100000.0f * (mi * mask[j] - 1.0f);
        const float4* k4  = (const float4*)(k     + (size_t)j * Hn * Cn);
        const float4* kp4 = (const float4*)(k_pts + (size_t)j * Hn * PQn * 3);
        #pragma unroll
        for (int h = 0; h < 12; ++h) {
            float qk = 0.f;
            #pragma unroll
            for (int c4 = 0; c4 < 4; ++c4) {
                float4 kv = k4[h*4 + c4];
                qk += kv.x * qrow[h*16 + c4*4 + 0] + kv.y * qrow[h*16 + c4*4 + 1]
                    + kv.z * qrow[h*16 + c4*4 + 2] + kv.w * qrow[h*16 + c4*4 + 3];
            }
            float4 A = kp4[h*3+0], Bv = kp4[h*3+1], Cv = kp4[h*3+2];
            const float* qp = qprow + h * 12;
            float d0 = qp[0]-A.x,  d1 = qp[1]-A.y,  d2 = qp[2]-A.z;
            float d3 = qp[3]-A.w,  d4 = qp[4]-Bv.x, d5 = qp[5]-Bv.y;
            float d6 = qp[6]-Bv.z, d7 = qp[7]-Bv.w, d8 = qp[8]-Cv.x;
            float d9 = qp[9]-Cv.y, dA = qp[10]-Cv.z, dB = qp[11]-Cv.w;
            float d2s = d0*d0+d1*d1+d2*d2+d3*d3+d4*d4+d5*d5
                      + d6*d6+d7*d7+d8*d8+d9*d9+dA*dA+dB*dB;
            lg[h*LGS + j] = S_QK*qk + S_B*bh[h] + coef[h]*d2s + mterm;
        }
    }
    __syncthreads();

    // ---------------- Phase B: softmax over j (wave w owns 3 heads) --------
    {
        const int w = t >> 6, l = t & 63;
        for (int hh = 0; hh < 3; ++hh) {
            const int h = w * 3 + hh;
            float e[12];
            #pragma unroll
            for (int u = 0; u < 12; ++u) e[u] = lg[h*LGS + l + u*64];
            float m = -1e30f;
            #pragma unroll
            for (int u = 0; u < 12; ++u) m = fmaxf(m, e[u]);
            #pragma unroll
            for (int off = 32; off > 0; off >>= 1) m = fmaxf(m, __shfl_xor(m, off));
            float ssum = 0.f;
            #pragma unroll
            for (int u = 0; u < 12; ++u) { e[u] = expf(e[u] - m); ssum += e[u]; }
            #pragma unroll
            for (int off = 32; off > 0; off >>= 1) ssum += __shfl_xor(ssum, off);
            const float inv = 1.0f / ssum;
            #pragma unroll
            for (int u = 0; u < 12; ++u) lg[h*LGS + l + u*64] = e[u] * inv;
        }
    }
    __syncthreads();

    // ---------------- Phase C: o_pair = a . z  (z row hits L2) -------------
    {
        const int half = t >> 7, tt = t & 127;
        const int hset = tt >> 5, c4 = tt & 31;
        const float* zb = z + (size_t)i * NN * CZn + c4 * 4;
        float acc[3][4];
        #pragma unroll
        for (int a_ = 0; a_ < 3; ++a_) { acc[a_][0]=0; acc[a_][1]=0; acc[a_][2]=0; acc[a_][3]=0; }
        const int j0 = half * 384;
        for (int jt = 0; jt < 48; ++jt) {
            const int jb = j0 + jt * 8;
            float aa[3][8];
            #pragma unroll
            for (int hh = 0; hh < 3; ++hh) {
                *(float4*)&aa[hh][0] = *(float4*)&lg[(hset*3+hh)*LGS + jb];
                *(float4*)&aa[hh][4] = *(float4*)&lg[(hset*3+hh)*LGS + jb + 4];
            }
            #pragma unroll
            for (int u = 0; u < 8; ++u) {
                float4 zv = *(const float4*)(zb + (size_t)(jb + u) * CZn);
                #pragma unroll
                for (int hh = 0; hh < 3; ++hh) {
                    acc[hh][0] += aa[hh][u] * zv.x;
                    acc[hh][1] += aa[hh][u] * zv.y;
                    acc[hh][2] += aa[hh][u] * zv.z;
                    acc[hh][3] += aa[hh][u] * zv.w;
                }
            }
        }
        #pragma unroll
        for (int hh = 0; hh < 3; ++hh)
            #pragma unroll
            for (int cc = 0; cc < 4; ++cc)
                part[half][(hset*3+hh)*CZn + c4*4 + cc] = acc[hh][cc];
    }

    // ---------------- o (H*C=192) and o_pt (288) accumulators --------------
    {
        float acc1 = 0.f, acc2 = 0.f;
        const float* src1; int str1, h1;
        if (t < 192) { src1 = v + t;            str1 = 192; h1 = t >> 4; }
        else         { const int p = t - 192; src1 = v_pts + p; str1 = 288; h1 = p / 24; }
        const bool has2 = (t < 224);
        const int p2 = t + 64;                 // second slice: ptsum[64..288)
        const float* src2 = v_pts + p2;
        const int h2 = p2 / 24;
        for (int jt = 0; jt < 96; ++jt) {
            const int jb = jt * 8;
            float a1[8], a2[8];
            *(float4*)&a1[0] = *(float4*)&lg[h1*LGS + jb];
            *(float4*)&a1[4] = *(float4*)&lg[h1*LGS + jb + 4];
            if (has2) {
                *(float4*)&a2[0] = *(float4*)&lg[h2*LGS + jb];
                *(float4*)&a2[4] = *(float4*)&lg[h2*LGS + jb + 4];
            }
            #pragma unroll
            for (int u = 0; u < 8; ++u) {
                acc1 += a1[u] * src1[(size_t)(jb + u) * str1];
                if (has2) acc2 += a2[u] * src2[(size_t)(jb + u) * 288];
            }
        }
        float* catr = cat + (size_t)i * CONCATn;
        if (t < 192) catr[t] = acc1;
        else         ptsum[t - 192] = acc1;
        if (has2)    ptsum[t + 64] = acc2;
        __syncthreads();

        // o_pair -> cat[576 .. 2111]
        for (int x = t; x < Hn * CZn; x += 256)
            catr[576 + x] = part[0][x] + part[1][x];

        // o_pt: invert frame, write 3 coord slices + norms
        if (t < 96) {
            const float gx = ptsum[t*3+0] - trans[i*3+0];
            const float gy = ptsum[t*3+1] - trans[i*3+1];
            const float gz = ptsum[t*3+2] - trans[i*3+2];
            const float lx = rot[i*9+0]*gx + rot[i*9+3]*gy + rot[i*9+6]*gz;
            const float ly = rot[i*9+1]*gx + rot[i*9+4]*gy + rot[i*9+7]*gz;
            const float lz = rot[i*9+2]*gx + rot[i*9+5]*gy + rot[i*9+8]*gz;
            catr[192 + t] = lx;
            catr[288 + t] = ly;
            catr[384 + t] = lz;
            catr[480 + t] = sqrtf(lx*lx + ly*ly + lz*lz + 1e-8f);
        }
    }
}

// ---------------------------------------------------------------------------
// Kernel 3: out = cat @ Wout + bout.  Grid (192 row-tiles x 3 col-tiles).
// ---------------------------------------------------------------------------
__global__ __launch_bounds__(256) void out_kernel(
    const float* __restrict__ cat, const float* __restrict__ Wout,
    const float* __restrict__ bout, float* __restrict__ out)
{
    const int rt = blockIdx.x;     // 0..191 : 4 rows each
    const int ot = blockIdx.y;     // 0..2   : 128 outputs each
    __shared__ float cl[4 * CONCATn];   // 33792 B
    const int r0 = rt * 4;
    const float4* cb = (const float4*)(cat + (size_t)r0 * CONCATn);
    for (int idx = threadIdx.x; idx < CONCATn; idx += 256)
        ((float4*)cl)[idx] = cb[idx];
    __syncthreads();

    const int t = threadIdx.x;
    const int o = ot * 128 + (t & 63) * 2;
    const int r = t >> 6;
    float ax = 0.f, ay = 0.f;
    const float* wp = Wout + o;
    const float* cr = cl + r * CONCATn;
    #pragma unroll 4
    for (int kk = 0; kk < CONCATn; ++kk) {
        float2 w = *(const float2*)(wp + (size_t)kk * 384);
        float cv = cr[kk];
        ax += cv * w.x; ay += cv * w.y;
    }
    const float2 bo = *(const float2*)(bout + o);
    float2 res; res.x = ax + bo.x; res.y = ay + bo.y;
    *(float2*)(out + (size_t)(r0 + r) * 384 + o) = res;
}

// ---------------------------------------------------------------------------
extern "C" void kernel_launch(void* const* d_in, const int* in_sizes, int n_in,
                              void* d_out, int out_size, void* d_ws, size_t ws_size,
                              hipStream_t stream)
{
    const float* s     = (const float*)d_in[0];
    const float* z     = (const float*)d_in[1];
    const float* rot   = (const float*)d_in[2];
    const float* trans = (const float*)d_in[3];
    const float* mask  = (const float*)d_in[4];
    const float* Wq    = (const float*)d_in[5];
    const float* bq    = (const float*)d_in[6];
    const float* Wkv   = (const float*)d_in[7];
    const float* bkv   = (const float*)d_in[8];
    const float* Wqp   = (const float*)d_in[9];
    const float* bqp   = (const float*)d_in[10];
    const float* Wkvp  = (const float*)d_in[11];
    const float* bkvp  = (const float*)d_in[12];
    const float* Wb    = (const float*)d_in[13];
    const float* bb    = (const float*)d_in[14];
    const float* head_w= (const float*)d_in[15];
    const float* Wout  = (const float*)d_in[16];
    const float* bout  = (const float*)d_in[17];
    float* out = (float*)d_out;

    float* ws    = (float*)d_ws;
    float* q     = ws;                  // 768*192   = 147456
    float* k     = q     + 147456;      // 147456
    float* v     = k     + 147456;      // 147456
    float* q_pts = v     + 147456;      // 768*144   = 110592
    float* k_pts = q_pts + 110592;      // 110592
    float* v_pts = k_pts + 110592;      // 768*288   = 221184
    float* cat   = v_pts + 221184;      // 768*2112  = 1622016  (total ~9.6 MB)

    hipLaunchKernelGGL(proj_kernel, dim3(96), dim3(256), 0, stream,
        s, rot, trans, Wq, bq, Wkv, bkv, Wqp, bqp, Wkvp, bkvp,
        q, k, v, q_pts, k_pts, v_pts);
    hipLaunchKernelGGL(row_kernel, dim3(NN), dim3(256), 0, stream,
        z, mask, rot, trans, q, k, v, q_pts, k_pts, v_pts, Wb, bb, head_w, cat);
    hipLaunchKernelGGL(out_kernel, dim3(192, 3), dim3(256), 0, stream,
        cat, Wout, bout, out);
}